// Round 3
// baseline (250.380 us; speedup 1.0000x reference)
//
#include <hip/hip_runtime.h>
#include <hip/hip_bf16.h>

typedef __bf16 bf16x8 __attribute__((ext_vector_type(8)));
typedef float f32x4 __attribute__((ext_vector_type(4)));

// row-pair XOR swizzle: logical (row n of 64B, 16B-chunk k) -> byte offset
__device__ __forceinline__ int swz(int n, int k) {
  int pair = n >> 1;
  int s = (((n & 1) << 2) | k) ^ (pair & 7);
  return (pair << 7) + (s << 4);
}

__device__ __forceinline__ void load_lds16(const void* g, void* l) {
  __builtin_amdgcn_global_load_lds((const __attribute__((address_space(1))) void*)g,
                                   (__attribute__((address_space(3))) void*)l, 16, 0, 0);
}

// ---------- zero the 1-px halo border of padded xn [b*4+grp][98][98][32] ----------
__global__ __launch_bounds__(256) void zero_border_kernel(__hip_bfloat16* __restrict__ xn) {
  int bg = blockIdx.x;                 // 0..127
  __hip_bfloat16* base = xn + (size_t)bg * 307328;
  for (int u = threadIdx.x; u < 1552; u += 256) {
    int cell = u >> 2, k = u & 3;
    int ph, pw;
    if (cell < 98)       { ph = 0;              pw = cell; }
    else if (cell < 196) { ph = 97;             pw = cell - 98; }
    else if (cell < 292) { ph = cell - 196 + 1; pw = 0; }
    else                 { ph = cell - 292 + 1; pw = 97; }
    *(uint4*)(base + ((size_t)ph * 98 + pw) * 32 + k * 8) = make_uint4(0, 0, 0, 0);
  }
}

// ---------- prep_x: f32 NCHW -> bf16 padded [b][grp4][98][98][32ic] ----------
__global__ __launch_bounds__(512) void prep_x_kernel(const float* __restrict__ x,
                                                     __hip_bfloat16* __restrict__ xn) {
  __shared__ float tile[128][97];
  int h = blockIdx.x;   // 0..95
  int b = blockIdx.y;   // 0..31
  const float* src = x + (size_t)b * 128 * 9216 + h * 96;
  for (int f = threadIdx.x; f < 3072; f += 512) {   // 128 ic x 24 float4
    int ic = f / 24, w4 = f - ic * 24;
    float4 v = *(const float4*)(src + (size_t)ic * 9216 + w4 * 4);
    tile[ic][w4 * 4 + 0] = v.x; tile[ic][w4 * 4 + 1] = v.y;
    tile[ic][w4 * 4 + 2] = v.z; tile[ic][w4 * 4 + 3] = v.w;
  }
  __syncthreads();
  __hip_bfloat16* dst = xn + (size_t)b * 4 * 307328 + (h + 1) * 3136 + 32;
  for (int o = threadIdx.x; o < 1536; o += 512) {   // 16B units
    int grp = o / 384, rem = o - grp * 384;
    int w = rem >> 2, chunk = rem & 3;
    __hip_bfloat16 tmp[8];
    #pragma unroll
    for (int e = 0; e < 8; e++) tmp[e] = __float2bfloat16(tile[grp * 32 + chunk * 8 + e][w]);
    *(uint4*)(dst + (size_t)grp * 307328 + w * 32 + chunk * 8) = *(uint4*)tmp;
  }
}

// ---------- prep_gpd: gate/pw/dw projections of z ----------
__global__ __launch_bounds__(256) void prep_gpd_kernel(
    const float* __restrict__ z, const float* __restrict__ gw,
    const float* __restrict__ pww, const float* __restrict__ dww,
    float* __restrict__ gate, float* __restrict__ pwv, float* __restrict__ dwv) {
  __shared__ float zs[32 * 64];
  for (int i = threadIdx.x; i < 32 * 64; i += 256) zs[i] = z[i];
  __syncthreads();
  int j = blockIdx.x * 256 + threadIdx.x;   // 0..17663
  const float* wrow; float* outp; int stride;
  if (j < 16384)             { wrow = pww + (size_t)j * 64;            outp = pwv + j;            stride = 16384; }
  else if (j < 16384 + 1152) { int jj = j - 16384; wrow = dww + (size_t)jj * 64; outp = dwv + jj; stride = 1152; }
  else                       { int jj = j - 17536; wrow = gw  + (size_t)jj * 64; outp = gate + jj; stride = 128; }
  float wr[64];
  #pragma unroll
  for (int i = 0; i < 16; i++) {
    float4 v = ((const float4*)wrow)[i];
    wr[4*i] = v.x; wr[4*i+1] = v.y; wr[4*i+2] = v.z; wr[4*i+3] = v.w;
  }
  for (int b = 0; b < 32; b++) {
    float acc = 0.f;
    #pragma unroll
    for (int i = 0; i < 64; i++) acc += zs[b * 64 + i] * wr[i];
    outp[(size_t)b * stride] = acc;
  }
}

// ---------- prep_w: merged weights -> Wt[b][grp4][tap9][oc128][32ic] bf16 ----------
__global__ __launch_bounds__(256) void prep_w_kernel(
    const float* __restrict__ base, const float* __restrict__ gate,
    const float* __restrict__ pwv, const float* __restrict__ dwv,
    __hip_bfloat16* __restrict__ Wt) {
  int blk = blockIdx.x;          // 1024 = 32 b x 32 ocg(4 oc)
  int b = blk >> 5, ocg = blk & 31;
  for (int e = threadIdx.x; e < 2304; e += 256) {
    int icL2 = e & 15;
    int r1 = e >> 4;
    int ocl = r1 & 3;
    int gt = r1 >> 2;            // grp*9+tap
    int grp = gt / 9, tap = gt - grp * 9;
    int oc = ocg * 4 + ocl;
    int ic = grp * 32 + icL2 * 2;
    float g = gate[b * 128 + oc];
    float d = dwv[b * 1152 + oc * 9 + tap];
    const float* bp = base + ((size_t)(oc * 128 + ic)) * 9 + tap;
    const float* pp = pwv + (size_t)b * 16384 + oc * 128 + ic;
    __hip_bfloat162 o2 = {__float2bfloat16(bp[0] * g + pp[0] * d),
                          __float2bfloat16(bp[9] * g + pp[1] * d)};
    *(__hip_bfloat162*)(Wt + ((((size_t)(b * 4 + grp) * 9 + tap) * 128 + oc) * 32 + icL2 * 2)) = o2;
  }
}

// ---------- conv: per-sample implicit GEMM, 256px x 64oc per block, pipelined ----------
__global__ __launch_bounds__(256, 4) void conv_kernel(
    const __hip_bfloat16* __restrict__ xn, const __hip_bfloat16* __restrict__ Wt,
    float* __restrict__ out) {
  __shared__ __align__(16) char smem[32768];
  char* xt  = smem;            // 1536 slots x 16B (uses 1360) = 24576 B
  char* wtb = smem + 24576;    // 2 x 4096 B weight tap buffers

  int bid = blockIdx.x;
  int X = bid & 7, q = bid >> 3;          // XCD grouping: 288 blocks (4 samples) per XCD
  int logical = X * 288 + q;
  int b   = logical / 72;
  int rem = logical - b * 72;
  int ocg = rem & 1;
  int t36 = rem >> 1;
  int hr  = t36 / 3;
  int wc  = t36 - hr * 3;
  int h0 = hr * 8, w0 = wc * 32;

  int tid = threadIdx.x;
  int lane = tid & 63, wid = tid >> 6;
  int l15 = lane & 15, lk = lane >> 4;

  // per-lane inverse-swizzled global source offsets (LDS dest stays linear)
  int xoff[6];
  #pragma unroll
  for (int j = 0; j < 6; j++) {
    int p = j * 256 + tid;
    int pair = p >> 3, v = (p & 7) ^ (pair & 7);
    int n = (pair << 1) | (v >> 2), k = v & 3;
    int hh = n / 34, ww = n - hh * 34;
    xoff[j] = ((h0 + hh) * 98 + (w0 + ww)) * 32 + k * 8;
  }
  int woff;
  {
    int p = tid;
    int pair = p >> 3, v = (p & 7) ^ (pair & 7);
    int n = (pair << 1) | (v >> 2), k = v & 3;
    woff = (ocg * 64 + n) * 32 + k * 8;
  }

  const __hip_bfloat16* xb = xn + (size_t)b * 4 * 307328;
  const __hip_bfloat16* wb = Wt + (size_t)b * 147456;

  f32x4 acc[4][4];
  #pragma unroll
  for (int i = 0; i < 4; i++)
    #pragma unroll
    for (int j = 0; j < 4; j++) acc[i][j] = (f32x4){0.f, 0.f, 0.f, 0.f};

  // prologue: x tile for grp 0 + weight tap for step 0
  #pragma unroll
  for (int j = 0; j < 6; j++) {
    int p = j * 256 + tid;
    if (p < 1360) load_lds16(xb + xoff[j], xt + ((j * 256 + wid * 64) << 4));
  }
  load_lds16(wb + woff, wtb + (wid << 10));

  #pragma unroll
  for (int s = 0; s < 36; s++) {
    const int grp = s / 9, t = s - grp * 9, dy = t / 3, dx = t - dy * 3;
    __builtin_amdgcn_s_barrier();            // prev step done reading buffers
    if (t == 0 && s) {
      const __hip_bfloat16* xg = xb + (size_t)grp * 307328;
      #pragma unroll
      for (int j = 0; j < 6; j++) {
        int p = j * 256 + tid;
        if (p < 1360) load_lds16(xg + xoff[j], xt + ((j * 256 + wid * 64) << 4));
      }
    }
    if (s < 35) {
      const int sn = s + 1, g2 = sn / 9, t2 = sn - g2 * 9;
      load_lds16(wb + (size_t)g2 * 36864 + t2 * 4096 + woff,
                 wtb + (((s + 1) & 1) << 12) + (wid << 10));
      asm volatile("s_waitcnt vmcnt(1)" ::: "memory");   // cur tap + x landed; next tap in flight
    } else {
      asm volatile("s_waitcnt vmcnt(0)" ::: "memory");
    }
    __builtin_amdgcn_s_barrier();            // tiles valid for all waves
    const char* wtc = wtb + ((s & 1) << 12);
    bf16x8 bfr[4], afr[4];
    #pragma unroll
    for (int j = 0; j < 4; j++)
      bfr[j] = *(const bf16x8*)(wtc + swz(j * 16 + l15, lk));
    #pragma unroll
    for (int i = 0; i < 4; i++) {
      int r = wid * 2 + (i >> 1) + dy;
      int c = ((i & 1) << 4) + l15 + dx;
      afr[i] = *(const bf16x8*)(xt + swz(r * 34 + c, lk));
    }
    __builtin_amdgcn_s_setprio(1);
    #pragma unroll
    for (int i = 0; i < 4; i++)
      #pragma unroll
      for (int j = 0; j < 4; j++)
        acc[i][j] = __builtin_amdgcn_mfma_f32_16x16x32_bf16(afr[i], bfr[j], acc[i][j], 0, 0, 0);
    __builtin_amdgcn_s_setprio(0);
  }

  // epilogue: each lane's f32x4 = 4 consecutive w at fixed (oc,h)
  float* ob = out + ((size_t)b * 128 + ocg * 64) * 9216;
  #pragma unroll
  for (int i = 0; i < 4; i++) {
    int m0 = wid * 64 + i * 16;
    int hrow = h0 + (m0 >> 5);
    int wcol = w0 + (m0 & 31) + lk * 4;
    #pragma unroll
    for (int j = 0; j < 4; j++) {
      int oc = j * 16 + l15;
      *(f32x4*)(ob + (size_t)oc * 9216 + hrow * 96 + wcol) = acc[i][j];
    }
  }
}

extern "C" void kernel_launch(void* const* d_in, const int* in_sizes, int n_in,
                              void* d_out, int out_size, void* d_ws, size_t ws_size,
                              hipStream_t stream) {
  const float* x   = (const float*)d_in[0];
  const float* z   = (const float*)d_in[1];
  const float* bw  = (const float*)d_in[2];
  const float* gw  = (const float*)d_in[3];
  const float* pww = (const float*)d_in[4];
  const float* dww = (const float*)d_in[5];
  float* out = (float*)d_out;

  char* ws = (char*)d_ws;
  __hip_bfloat16* xn = (__hip_bfloat16*)ws;                       // 78,675,968 B (padded)
  __hip_bfloat16* Wt = (__hip_bfloat16*)(ws + 78675968);          //  9,437,184 B
  float* gate = (float*)(ws + 78675968 + 9437184);                // 32*128
  float* pwv  = gate + 32 * 128;                                  // 32*16384
  float* dwv  = pwv + 32 * 16384;                                 // 32*1152

  hipLaunchKernelGGL(zero_border_kernel, dim3(128), dim3(256), 0, stream, xn);
  hipLaunchKernelGGL(prep_x_kernel,  dim3(96, 32), dim3(512), 0, stream, x, xn);
  hipLaunchKernelGGL(prep_gpd_kernel, dim3(69, 1, 1), dim3(256), 0, stream,
                     z, gw, pww, dww, gate, pwv, dwv);
  hipLaunchKernelGGL(prep_w_kernel,  dim3(1024, 1, 1), dim3(256), 0, stream,
                     bw, gate, pwv, dwv, Wt);
  hipLaunchKernelGGL(conv_kernel,    dim3(2304, 1, 1), dim3(256), 0, stream, xn, Wt, out);
}

// Round 4
// 166.470 us; speedup vs baseline: 1.5041x; 1.5041x over previous
//
#include <hip/hip_runtime.h>
#include <hip/hip_bf16.h>

typedef __bf16 bf16x8 __attribute__((ext_vector_type(8)));
typedef float f32x4 __attribute__((ext_vector_type(4)));

// row-pair XOR swizzle: logical (row n of 64B, 16B-chunk k) -> byte offset
__device__ __forceinline__ int swz(int n, int k) {
  int pair = n >> 1;
  int s = (((n & 1) << 2) | k) ^ (pair & 7);
  return (pair << 7) + (s << 4);
}

__device__ __forceinline__ void load_lds16(const void* g, void* l) {
  __builtin_amdgcn_global_load_lds((const __attribute__((address_space(1))) void*)g,
                                   (__attribute__((address_space(3))) void*)l, 16, 0, 0);
}

// ---------- prep_x: f32 NCHW -> bf16 padded [b][grp4][98][98][32ic], border-zero fused ----------
__global__ __launch_bounds__(512) void prep_x_kernel(const float* __restrict__ x,
                                                     __hip_bfloat16* __restrict__ xn) {
  __shared__ float tile[128][97];
  int h = blockIdx.x;   // 0..95
  int b = blockIdx.y;   // 0..31
  const float* src = x + (size_t)b * 128 * 9216 + h * 96;
  for (int f = threadIdx.x; f < 3072; f += 512) {   // 128 ic x 24 float4
    int ic = f / 24, w4 = f - ic * 24;
    float4 v = *(const float4*)(src + (size_t)ic * 9216 + w4 * 4);
    tile[ic][w4 * 4 + 0] = v.x; tile[ic][w4 * 4 + 1] = v.y;
    tile[ic][w4 * 4 + 2] = v.z; tile[ic][w4 * 4 + 3] = v.w;
  }
  __syncthreads();
  __hip_bfloat16* bb  = xn + (size_t)b * 4 * 307328;
  __hip_bfloat16* dst = bb + (h + 1) * 3136 + 32;
  for (int o = threadIdx.x; o < 1536; o += 512) {   // 16B units
    int grp = o / 384, rem = o - grp * 384;
    int w = rem >> 2, chunk = rem & 3;
    __hip_bfloat16 tmp[8];
    #pragma unroll
    for (int e = 0; e < 8; e++) tmp[e] = __float2bfloat16(tile[grp * 32 + chunk * 8 + e][w]);
    *(uint4*)(dst + (size_t)grp * 307328 + w * 32 + chunk * 8) = *(uint4*)tmp;
  }
  // left/right halo cells of this row (ph = h+1)
  if (threadIdx.x < 32) {
    int u = threadIdx.x;
    int grp = u >> 3, rem = u & 7;
    int pw = (rem >> 2) ? 97 : 0, k = rem & 3;
    *(uint4*)(bb + (size_t)grp * 307328 + ((h + 1) * 98 + pw) * 32 + k * 8) = make_uint4(0, 0, 0, 0);
  }
  // top/bottom halo rows
  if (h == 0 || h == 95) {
    int ph = (h == 0) ? 0 : 97;
    for (int u = threadIdx.x; u < 1568; u += 512) {
      int grp = u / 392, rem = u - grp * 392;
      int pw = rem >> 2, k = rem & 3;
      *(uint4*)(bb + (size_t)grp * 307328 + (ph * 98 + pw) * 32 + k * 8) = make_uint4(0, 0, 0, 0);
    }
  }
}

// ---------- prep_w fused: z projections + merge -> Wt[b][grp4][tap9][oc128][32ic] bf16 ----------
__global__ __launch_bounds__(256) void prep_w_kernel(
    const float* __restrict__ z, const float* __restrict__ gw,
    const float* __restrict__ pww, const float* __restrict__ dww,
    const float* __restrict__ base, __hip_bfloat16* __restrict__ Wt) {
  __shared__ float zs[2048];
  __shared__ float res[138][33];   // row 0=gate, 1..9=dw taps, 10..137=pw ic
  int oc = blockIdx.x;             // 0..127
  for (int i = threadIdx.x; i < 2048; i += 256) zs[i] = z[i];
  __syncthreads();
  int row = threadIdx.x;
  if (row < 138) {
    const float* wrow = (row == 0) ? gw + (size_t)oc * 64
                      : (row < 10) ? dww + ((size_t)oc * 9 + (row - 1)) * 64
                                   : pww + ((size_t)oc * 128 + (row - 10)) * 64;
    float wr[64];
    #pragma unroll
    for (int i = 0; i < 16; i++) {
      float4 v = ((const float4*)wrow)[i];
      wr[4*i] = v.x; wr[4*i+1] = v.y; wr[4*i+2] = v.z; wr[4*i+3] = v.w;
    }
    for (int b = 0; b < 32; b++) {
      float a = 0.f;
      #pragma unroll
      for (int i = 0; i < 64; i++) a += zs[b * 64 + i] * wr[i];
      res[row][b] = a;
    }
  }
  __syncthreads();
  for (int e = threadIdx.x; e < 18432; e += 256) {   // bf162 units
    int icp = e & 15;
    int r1 = e >> 4;
    int tap = r1 % 9, bg = r1 / 9;       // bg = b*4+grp
    int grp = bg & 3, b = bg >> 2;
    int ic = grp * 32 + icp * 2;
    float g = res[0][b], d = res[1 + tap][b];
    float p0 = res[10 + ic][b], p1 = res[11 + ic][b];
    const float* bp = base + ((size_t)(oc * 128 + ic)) * 9 + tap;
    __hip_bfloat162 o2 = {__float2bfloat16(bp[0] * g + p0 * d),
                          __float2bfloat16(bp[9] * g + p1 * d)};
    *(__hip_bfloat162*)(Wt + (((size_t)bg * 9 + tap) * 128 + oc) * 32 + icp * 2) = o2;
  }
}

// ---------- conv: 256px x 64oc per block, 12-phase pipelined (x dbuf + w dbuf) ----------
__global__ __launch_bounds__(256, 2) void conv_kernel(
    const __hip_bfloat16* __restrict__ xn, const __hip_bfloat16* __restrict__ Wt,
    float* __restrict__ out) {
  __shared__ __align__(16) char smem[73728];
  char* const xb0 = smem;               // 24576 B (1536 slots; 1360 used)
  char* const xb1 = smem + 24576;
  char* const wb0 = smem + 49152;       // 12288 B each
  char* const wb1 = smem + 61440;

  int bid = blockIdx.x;
  int X = bid & 7, q = bid >> 3;        // XCD grouping: 4 samples per XCD
  int logical = X * 288 + q;
  int b   = logical / 72;
  int rem = logical - b * 72;
  int ocg = rem & 1;
  int t36 = rem >> 1;
  int hr  = t36 / 3;
  int wc  = t36 - hr * 3;
  int h0 = hr * 8, w0 = wc * 32;

  int tid = threadIdx.x;
  int lane = tid & 63, wid = tid >> 6;
  int l15 = lane & 15, lk = lane >> 4;

  // x-stage source offsets (6/thread, clamp keeps per-wave issue count uniform)
  int xoff[6];
  #pragma unroll
  for (int j = 0; j < 6; j++) {
    int p = j * 256 + tid; if (p > 1359) p = 1359;
    int pair = p >> 3, v = (p & 7) ^ (pair & 7);
    int n = (pair << 1) | (v >> 2), k = v & 3;
    int hh = n / 34, ww = n - hh * 34;
    xoff[j] = ((h0 + hh) * 98 + (w0 + ww)) * 32 + k * 8;
  }
  // w-stage source offsets (3/thread), relative to the phase's 3-tap block
  int wsoff[3];
  #pragma unroll
  for (int i = 0; i < 3; i++) {
    int p = i * 256 + tid;
    int pair = p >> 3, v = (p & 7) ^ (pair & 7);
    int n = (pair << 1) | (v >> 2), k = v & 3;
    int dx = n >> 6, ocl = n & 63;
    wsoff[i] = (dx * 128 + ocg * 64 + ocl) * 32 + k * 8;
  }

  const __hip_bfloat16* xbase = xn + (size_t)b * 4 * 307328;
  const __hip_bfloat16* wbase = Wt + (size_t)b * 147456;

  f32x4 acc[4][4];
  #pragma unroll
  for (int i = 0; i < 4; i++)
    #pragma unroll
    for (int j = 0; j < 4; j++) acc[i][j] = (f32x4){0.f, 0.f, 0.f, 0.f};

  // prologue: x(grp0) -> xb0, w(phase0) -> wb0
  #pragma unroll
  for (int j = 0; j < 6; j++)
    load_lds16(xbase + xoff[j], xb0 + ((j * 256 + wid * 64) << 4));
  #pragma unroll
  for (int i = 0; i < 3; i++)
    load_lds16(wbase + wsoff[i], wb0 + ((i * 256 + wid * 64) << 4));

#define PHASE(G, T, XCUR, XNXT, WCUR, WNXT, DOX, DOW, VM)                          \
  {                                                                                \
    __builtin_amdgcn_s_barrier();                                                  \
    if (DOW) {                                                                     \
      const __hip_bfloat16* wsrc = wbase + (size_t)((G) * 9 + (T) * 3 + 3) * 4096; \
      _Pragma("unroll")                                                            \
      for (int i = 0; i < 3; i++)                                                  \
        load_lds16(wsrc + wsoff[i], (WNXT) + ((i * 256 + wid * 64) << 4));         \
    }                                                                              \
    if (DOX) {                                                                     \
      const __hip_bfloat16* xsrc = xbase + (size_t)((G) + 1) * 307328;             \
      _Pragma("unroll")                                                            \
      for (int j = 0; j < 6; j++)                                                  \
        load_lds16(xsrc + xoff[j], (XNXT) + ((j * 256 + wid * 64) << 4));          \
    }                                                                              \
    asm volatile("s_waitcnt vmcnt(" #VM ")" ::: "memory");                         \
    __builtin_amdgcn_s_barrier();                                                  \
    _Pragma("unroll")                                                              \
    for (int dx = 0; dx < 3; dx++) {                                               \
      bf16x8 bfr[4], afr[4];                                                       \
      _Pragma("unroll")                                                            \
      for (int j = 0; j < 4; j++)                                                  \
        bfr[j] = *(const bf16x8*)((WCUR) + swz(dx * 64 + j * 16 + l15, lk));       \
      _Pragma("unroll")                                                            \
      for (int i = 0; i < 4; i++) {                                                \
        int r = wid * 2 + (i >> 1) + (T);                                          \
        int c = ((i & 1) << 4) + l15 + dx;                                         \
        afr[i] = *(const bf16x8*)((XCUR) + swz(r * 34 + c, lk));                   \
      }                                                                            \
      __builtin_amdgcn_s_setprio(1);                                               \
      _Pragma("unroll")                                                            \
      for (int i = 0; i < 4; i++)                                                  \
        _Pragma("unroll")                                                          \
        for (int j = 0; j < 4; j++)                                                \
          acc[i][j] = __builtin_amdgcn_mfma_f32_16x16x32_bf16(afr[i], bfr[j],      \
                                                              acc[i][j], 0, 0, 0); \
      __builtin_amdgcn_s_setprio(0);                                               \
    }                                                                              \
  }

  PHASE(0, 0, xb0, xb1, wb0, wb1, 1, 1, 9)
  PHASE(0, 1, xb0, xb1, wb1, wb0, 0, 1, 9)
  PHASE(0, 2, xb0, xb1, wb0, wb1, 0, 1, 3)
  PHASE(1, 0, xb1, xb0, wb1, wb0, 1, 1, 9)
  PHASE(1, 1, xb1, xb0, wb0, wb1, 0, 1, 9)
  PHASE(1, 2, xb1, xb0, wb1, wb0, 0, 1, 3)
  PHASE(2, 0, xb0, xb1, wb0, wb1, 1, 1, 9)
  PHASE(2, 1, xb0, xb1, wb1, wb0, 0, 1, 9)
  PHASE(2, 2, xb0, xb1, wb0, wb1, 0, 1, 3)
  PHASE(3, 0, xb1, xb0, wb1, wb0, 0, 1, 3)
  PHASE(3, 1, xb1, xb0, wb0, wb1, 0, 1, 3)
  PHASE(3, 2, xb1, xb0, wb1, wb0, 0, 0, 0)
#undef PHASE

  // epilogue: j-outer so each 128B output line completes in consecutive stores
  float* ob = out + ((size_t)b * 128 + ocg * 64) * 9216;
  #pragma unroll
  for (int j = 0; j < 4; j++) {
    int oc = j * 16 + l15;
    float* op = ob + (size_t)oc * 9216 + h0 * 96 + w0 + lk * 4;
    #pragma unroll
    for (int i = 0; i < 4; i++) {
      int m0 = wid * 64 + i * 16;
      *(f32x4*)(op + (m0 >> 5) * 96 + (m0 & 31)) = acc[i][j];
    }
  }
}

extern "C" void kernel_launch(void* const* d_in, const int* in_sizes, int n_in,
                              void* d_out, int out_size, void* d_ws, size_t ws_size,
                              hipStream_t stream) {
  const float* x   = (const float*)d_in[0];
  const float* z   = (const float*)d_in[1];
  const float* bw  = (const float*)d_in[2];
  const float* gw  = (const float*)d_in[3];
  const float* pww = (const float*)d_in[4];
  const float* dww = (const float*)d_in[5];
  float* out = (float*)d_out;

  char* ws = (char*)d_ws;
  __hip_bfloat16* xn = (__hip_bfloat16*)ws;                       // 78,675,968 B (padded)
  __hip_bfloat16* Wt = (__hip_bfloat16*)(ws + 78675968);          //  9,437,184 B

  hipLaunchKernelGGL(prep_x_kernel, dim3(96, 32), dim3(512), 0, stream, x, xn);
  hipLaunchKernelGGL(prep_w_kernel, dim3(128), dim3(256), 0, stream,
                     z, gw, pww, dww, bw, Wt);
  hipLaunchKernelGGL(conv_kernel,   dim3(2304), dim3(256), 0, stream, xn, Wt, out);
}

// Round 5
// 161.583 us; speedup vs baseline: 1.5496x; 1.0302x over previous
//
#include <hip/hip_runtime.h>
#include <hip/hip_bf16.h>

typedef __bf16 bf16x8 __attribute__((ext_vector_type(8)));
typedef float f32x4 __attribute__((ext_vector_type(4)));

// row-pair XOR swizzle: logical (row n of 64B, 16B-chunk k) -> byte offset
__device__ __forceinline__ int swz(int n, int k) {
  int pair = n >> 1;
  int s = (((n & 1) << 2) | k) ^ (pair & 7);
  return (pair << 7) + (s << 4);
}

__device__ __forceinline__ void load_lds16(const void* g, void* l) {
  __builtin_amdgcn_global_load_lds((const __attribute__((address_space(1))) void*)g,
                                   (__attribute__((address_space(3))) void*)l, 16, 0, 0);
}

// ---------- prep_x: f32 NCHW -> bf16 padded [b][grp4][98][98][32ic], border-zero fused ----------
__global__ __launch_bounds__(512) void prep_x_kernel(const float* __restrict__ x,
                                                     __hip_bfloat16* __restrict__ xn) {
  __shared__ float tile[128][97];
  int h = blockIdx.x;   // 0..95
  int b = blockIdx.y;   // 0..31
  const float* src = x + (size_t)b * 128 * 9216 + h * 96;
  for (int f = threadIdx.x; f < 3072; f += 512) {   // 128 ic x 24 float4
    int ic = f / 24, w4 = f - ic * 24;
    float4 v = *(const float4*)(src + (size_t)ic * 9216 + w4 * 4);
    tile[ic][w4 * 4 + 0] = v.x; tile[ic][w4 * 4 + 1] = v.y;
    tile[ic][w4 * 4 + 2] = v.z; tile[ic][w4 * 4 + 3] = v.w;
  }
  __syncthreads();
  __hip_bfloat16* bb  = xn + (size_t)b * 4 * 307328;
  __hip_bfloat16* dst = bb + (h + 1) * 3136 + 32;
  for (int o = threadIdx.x; o < 1536; o += 512) {   // 16B units
    int grp = o / 384, rem = o - grp * 384;
    int w = rem >> 2, chunk = rem & 3;
    __hip_bfloat16 tmp[8];
    #pragma unroll
    for (int e = 0; e < 8; e++) tmp[e] = __float2bfloat16(tile[grp * 32 + chunk * 8 + e][w]);
    *(uint4*)(dst + (size_t)grp * 307328 + w * 32 + chunk * 8) = *(uint4*)tmp;
  }
  // left/right halo cells of this row (ph = h+1)
  if (threadIdx.x < 32) {
    int u = threadIdx.x;
    int grp = u >> 3, rem = u & 7;
    int pw = (rem >> 2) ? 97 : 0, k = rem & 3;
    *(uint4*)(bb + (size_t)grp * 307328 + ((h + 1) * 98 + pw) * 32 + k * 8) = make_uint4(0, 0, 0, 0);
  }
  // top/bottom halo rows
  if (h == 0 || h == 95) {
    int ph = (h == 0) ? 0 : 97;
    for (int u = threadIdx.x; u < 1568; u += 512) {
      int grp = u / 392, rem = u - grp * 392;
      int pw = rem >> 2, k = rem & 3;
      *(uint4*)(bb + (size_t)grp * 307328 + (ph * 98 + pw) * 32 + k * 8) = make_uint4(0, 0, 0, 0);
    }
  }
}

// ---------- prep_w fused: z projections + merge -> Wt[b][grp4][tap9][oc128][32ic] bf16 ----------
__global__ __launch_bounds__(256) void prep_w_kernel(
    const float* __restrict__ z, const float* __restrict__ gw,
    const float* __restrict__ pww, const float* __restrict__ dww,
    const float* __restrict__ base, __hip_bfloat16* __restrict__ Wt) {
  __shared__ float zs[2048];
  __shared__ float res[138][33];   // row 0=gate, 1..9=dw taps, 10..137=pw ic
  int oc = blockIdx.x;             // 0..127
  for (int i = threadIdx.x; i < 2048; i += 256) zs[i] = z[i];
  __syncthreads();
  int row = threadIdx.x;
  if (row < 138) {
    const float* wrow = (row == 0) ? gw + (size_t)oc * 64
                      : (row < 10) ? dww + ((size_t)oc * 9 + (row - 1)) * 64
                                   : pww + ((size_t)oc * 128 + (row - 10)) * 64;
    float wr[64];
    #pragma unroll
    for (int i = 0; i < 16; i++) {
      float4 v = ((const float4*)wrow)[i];
      wr[4*i] = v.x; wr[4*i+1] = v.y; wr[4*i+2] = v.z; wr[4*i+3] = v.w;
    }
    for (int b = 0; b < 32; b++) {
      float a = 0.f;
      #pragma unroll
      for (int i = 0; i < 64; i++) a += zs[b * 64 + i] * wr[i];
      res[row][b] = a;
    }
  }
  __syncthreads();
  for (int e = threadIdx.x; e < 18432; e += 256) {   // bf162 units
    int icp = e & 15;
    int r1 = e >> 4;
    int tap = r1 % 9, bg = r1 / 9;       // bg = b*4+grp
    int grp = bg & 3, b = bg >> 2;
    int ic = grp * 32 + icp * 2;
    float g = res[0][b], d = res[1 + tap][b];
    float p0 = res[10 + ic][b], p1 = res[11 + ic][b];
    const float* bp = base + ((size_t)(oc * 128 + ic)) * 9 + tap;
    __hip_bfloat162 o2 = {__float2bfloat16(bp[0] * g + p0 * d),
                          __float2bfloat16(bp[9] * g + p1 * d)};
    *(__hip_bfloat162*)(Wt + (((size_t)bg * 9 + tap) * 128 + oc) * 32 + icp * 2) = o2;
  }
}

// ---------- conv: 256px x 64oc per block, 12-phase, x single-buf + w dbuf, 48KB LDS ----------
__global__ __launch_bounds__(256, 3) void conv_kernel(
    const __hip_bfloat16* __restrict__ xn, const __hip_bfloat16* __restrict__ Wt,
    float* __restrict__ out) {
  __shared__ __align__(16) char smem[49152];
  char* const xt  = smem;               // 24576 B (1536 slots; 1360 used)
  char* const wb0 = smem + 24576;       // 12288 B each
  char* const wb1 = smem + 36864;

  int bid = blockIdx.x;
  int X = bid & 7, q = bid >> 3;        // XCD grouping: 4 samples per XCD
  int logical = X * 288 + q;
  int b   = logical / 72;
  int rem = logical - b * 72;
  int ocg = rem & 1;
  int t36 = rem >> 1;
  int hr  = t36 / 3;
  int wc  = t36 - hr * 3;
  int h0 = hr * 8, w0 = wc * 32;

  int tid = threadIdx.x;
  int lane = tid & 63, wid = tid >> 6;
  int l15 = lane & 15, lk = lane >> 4;

  // x-stage source offsets (6/thread, clamp keeps per-wave issue count uniform)
  int xoff[6];
  #pragma unroll
  for (int j = 0; j < 6; j++) {
    int p = j * 256 + tid; if (p > 1359) p = 1359;
    int pair = p >> 3, v = (p & 7) ^ (pair & 7);
    int n = (pair << 1) | (v >> 2), k = v & 3;
    int hh = n / 34, ww = n - hh * 34;
    xoff[j] = ((h0 + hh) * 98 + (w0 + ww)) * 32 + k * 8;
  }
  // w-stage source offsets (3/thread), relative to the phase's 3-tap block
  int wsoff[3];
  #pragma unroll
  for (int i = 0; i < 3; i++) {
    int p = i * 256 + tid;
    int pair = p >> 3, v = (p & 7) ^ (pair & 7);
    int n = (pair << 1) | (v >> 2), k = v & 3;
    int dx = n >> 6, ocl = n & 63;
    wsoff[i] = (dx * 128 + ocg * 64 + ocl) * 32 + k * 8;
  }

  const __hip_bfloat16* xbase = xn + (size_t)b * 4 * 307328;
  const __hip_bfloat16* wbase = Wt + (size_t)b * 147456;

  f32x4 acc[4][4];
  #pragma unroll
  for (int i = 0; i < 4; i++)
    #pragma unroll
    for (int j = 0; j < 4; j++) acc[i][j] = (f32x4){0.f, 0.f, 0.f, 0.f};

  // prologue: w(phase0) -> wb0, then x(grp0) -> xt
  #pragma unroll
  for (int i = 0; i < 3; i++)
    load_lds16(wbase + wsoff[i], wb0 + ((i * 256 + wid * 64) << 4));
  #pragma unroll
  for (int j = 0; j < 6; j++)
    load_lds16(xbase + xoff[j], xt + ((j * 256 + wid * 64) << 4));

#define PHASE(G, T, WCUR, WNXT, DOX, DOW, VM)                                      \
  {                                                                                \
    __builtin_amdgcn_s_barrier();                                                  \
    if (DOX) {                                                                     \
      const __hip_bfloat16* xsrc = xbase + (size_t)(G) * 307328;                   \
      _Pragma("unroll")                                                            \
      for (int j = 0; j < 6; j++)                                                  \
        load_lds16(xsrc + xoff[j], xt + ((j * 256 + wid * 64) << 4));              \
    }                                                                              \
    if (DOW) {                                                                     \
      const __hip_bfloat16* wsrc = wbase + (size_t)((G) * 9 + (T) * 3 + 3) * 4096; \
      _Pragma("unroll")                                                            \
      for (int i = 0; i < 3; i++)                                                  \
        load_lds16(wsrc + wsoff[i], (WNXT) + ((i * 256 + wid * 64) << 4));         \
    }                                                                              \
    asm volatile("s_waitcnt vmcnt(" #VM ")" ::: "memory");                         \
    __builtin_amdgcn_s_barrier();                                                  \
    _Pragma("unroll")                                                              \
    for (int dx = 0; dx < 3; dx++) {                                               \
      bf16x8 bfr[4], afr[4];                                                       \
      _Pragma("unroll")                                                            \
      for (int j = 0; j < 4; j++)                                                  \
        bfr[j] = *(const bf16x8*)((WCUR) + swz(dx * 64 + j * 16 + l15, lk));       \
      _Pragma("unroll")                                                            \
      for (int i = 0; i < 4; i++) {                                                \
        int r = wid * 2 + (i >> 1) + (T);                                          \
        int c = ((i & 1) << 4) + l15 + dx;                                         \
        afr[i] = *(const bf16x8*)(xt + swz(r * 34 + c, lk));                       \
      }                                                                            \
      __builtin_amdgcn_s_setprio(1);                                               \
      _Pragma("unroll")                                                            \
      for (int i = 0; i < 4; i++)                                                  \
        _Pragma("unroll")                                                          \
        for (int j = 0; j < 4; j++)                                                \
          acc[i][j] = __builtin_amdgcn_mfma_f32_16x16x32_bf16(afr[i], bfr[j],      \
                                                              acc[i][j], 0, 0, 0); \
      __builtin_amdgcn_s_setprio(0);                                               \
    }                                                                              \
  }

  PHASE(0, 0, wb0, wb1, 0, 1, 3)
  PHASE(0, 1, wb1, wb0, 0, 1, 3)
  PHASE(0, 2, wb0, wb1, 0, 1, 3)
  PHASE(1, 0, wb1, wb0, 1, 1, 3)
  PHASE(1, 1, wb0, wb1, 0, 1, 3)
  PHASE(1, 2, wb1, wb0, 0, 1, 3)
  PHASE(2, 0, wb0, wb1, 1, 1, 3)
  PHASE(2, 1, wb1, wb0, 0, 1, 3)
  PHASE(2, 2, wb0, wb1, 0, 1, 3)
  PHASE(3, 0, wb1, wb0, 1, 1, 3)
  PHASE(3, 1, wb0, wb1, 0, 1, 3)
  PHASE(3, 2, wb1, wb0, 0, 0, 0)
#undef PHASE

  // epilogue: j-outer so each 128B output line completes in consecutive stores
  float* ob = out + ((size_t)b * 128 + ocg * 64) * 9216;
  #pragma unroll
  for (int j = 0; j < 4; j++) {
    int oc = j * 16 + l15;
    float* op = ob + (size_t)oc * 9216 + h0 * 96 + w0 + lk * 4;
    #pragma unroll
    for (int i = 0; i < 4; i++) {
      int m0 = wid * 64 + i * 16;
      *(f32x4*)(op + (m0 >> 5) * 96 + (m0 & 31)) = acc[i][j];
    }
  }
}

extern "C" void kernel_launch(void* const* d_in, const int* in_sizes, int n_in,
                              void* d_out, int out_size, void* d_ws, size_t ws_size,
                              hipStream_t stream) {
  const float* x   = (const float*)d_in[0];
  const float* z   = (const float*)d_in[1];
  const float* bw  = (const float*)d_in[2];
  const float* gw  = (const float*)d_in[3];
  const float* pww = (const float*)d_in[4];
  const float* dww = (const float*)d_in[5];
  float* out = (float*)d_out;

  char* ws = (char*)d_ws;
  __hip_bfloat16* xn = (__hip_bfloat16*)ws;                       // 78,675,968 B (padded)
  __hip_bfloat16* Wt = (__hip_bfloat16*)(ws + 78675968);          //  9,437,184 B

  hipLaunchKernelGGL(prep_x_kernel, dim3(96, 32), dim3(512), 0, stream, x, xn);
  hipLaunchKernelGGL(prep_w_kernel, dim3(128), dim3(256), 0, stream,
                     z, gw, pww, dww, bw, Wt);
  hipLaunchKernelGGL(conv_kernel,   dim3(2304), dim3(256), 0, stream, xn, Wt, out);
}